// Round 10
// baseline (276.903 us; speedup 1.0000x reference)
//
#include <hip/hip_runtime.h>
#include <cstdint>
#include <cstddef>

#define N_NODES 100000
#define N_EDGES 1600000
#define IN_CH   128
#define HID_CH  128
#define OUT_CH  64

#define AGG_BLOCKS 2048

#define SH    256
#define SHR   391        // ceil(100000/256)
#define BCAP  7200       // mean 6250, ~12 sigma slack
#define BK_CHUNK 4096
#define BK_NBLK ((N_EDGES + BK_CHUNK - 1) / BK_CHUNK)   // 391
#define GM_NBLK ((N_NODES + 127) / 128)                  // 782

__device__ __forceinline__ unsigned short f2bf(float f) {
    unsigned int u = __float_as_uint(f);
    unsigned int r = (u + 0x7FFFu + ((u >> 16) & 1u)) >> 16;   // RNE
    return (unsigned short)r;
}
__device__ __forceinline__ float bfbits2f(unsigned int lo16) {
    return __uint_as_float(lo16 << 16);
}

typedef __attribute__((ext_vector_type(8))) short bf16x8;
typedef __attribute__((ext_vector_type(4))) float f32x4;

// ---------------- fused kernel 1: bucket (blocks 0..390) ∥ gemm1 (391..1172) ----------------
// Bucket: scatter/memory-bound. Gemm1: MFMA-bound. Independent work, one dispatch.
__global__ __launch_bounds__(512) void k_fused1(const int* __restrict__ ei,
                                                int* __restrict__ gcur,
                                                long long* __restrict__ buckets,
                                                const float* __restrict__ A,
                                                const float* __restrict__ W,
                                                unsigned short* __restrict__ hb) {
    __shared__ __align__(16) unsigned char smem[64 * 1024];
    const int tid = threadIdx.x;

    if (blockIdx.x < BK_NBLK) {
        // ---- bucket path (R9 verbatim, LDS via smem) ----
        int (*scount)[SH] = (int(*)[SH])smem;                 // 8KB
        int (*sbase)[SH]  = (int(*)[SH])(smem + 8 * SH * 4);  // 8KB
        const int w    = tid >> 6;
        const int base = blockIdx.x * BK_CHUNK;
        for (int i = tid; i < 8 * SH; i += 512) ((int*)scount)[i] = 0;
        __syncthreads();
        int dv[8], sv[8], shd[8], rk[8];
        #pragma unroll
        for (int k = 0; k < 8; k++) {
            int e = base + k * 512 + tid;
            if (e < N_EDGES) {
                dv[k] = __builtin_nontemporal_load(ei + N_EDGES + e);
                sv[k] = __builtin_nontemporal_load(ei + e);
                shd[k] = dv[k] / SHR;
                rk[k] = atomicAdd(&scount[w][shd[k]], 1);
            } else shd[k] = -1;
        }
        __syncthreads();
        if (tid < SH) {
            int c[8], tot = 0;
            #pragma unroll
            for (int q = 0; q < 8; q++) { c[q] = scount[q][tid]; tot += c[q]; }
            int run = atomicAdd(&gcur[tid], tot);
            #pragma unroll
            for (int q = 0; q < 8; q++) { sbase[q][tid] = run; run += c[q]; }
        }
        __syncthreads();
        #pragma unroll
        for (int k = 0; k < 8; k++) {
            if (shd[k] >= 0) {
                int pos = sbase[w][shd[k]] + rk[k];
                if (pos < BCAP)
                    buckets[(size_t)shd[k] * BCAP + pos] =
                        ((long long)sv[k] << 32) | (unsigned int)dv[k];
            }
        }
        return;
    }

    // ---- gemm1 path: 8 waves x 16 rows, OC=128 ----
    unsigned short* As = (unsigned short*)smem;              // 32KB
    unsigned short* Ws = (unsigned short*)(smem + 32 * 1024);// 32KB
    const int l   = tid & 63;
    const int wv  = tid >> 6;                                // 0..7
    const int row0 = (blockIdx.x - BK_NBLK) * 128;

    #pragma unroll
    for (int it = 0; it < 8; it++) {
        int idx4 = it * 512 + tid;                           // 4096 float4
        int r = idx4 >> 5, c4 = idx4 & 31;
        int gr = row0 + r; if (gr >= N_NODES) gr = N_NODES - 1;
        float4 v = ((const float4*)(A + (size_t)gr * 128))[c4];
        int bi = (r * 128 + c4 * 4) ^ ((r & 7) << 3);
        ushort4 pk;
        pk.x = f2bf(v.x); pk.y = f2bf(v.y); pk.z = f2bf(v.z); pk.w = f2bf(v.w);
        *(ushort4*)&As[bi] = pk;
    }
    for (int idx = tid; idx < 128 * 128; idx += 512) {
        int k = idx >> 7, c = idx & 127;
        Ws[(c * 128 + k) ^ ((c & 7) << 3)] = f2bf(W[idx]);
    }
    __syncthreads();

    f32x4 acc[8];
    #pragma unroll
    for (int cf = 0; cf < 8; cf++) acc[cf] = {0.f, 0.f, 0.f, 0.f};
    const int fr = l & 15;
    const int kg = (l >> 4) * 8;

    #pragma unroll
    for (int ks = 0; ks < 4; ks++) {
        const int kk = ks * 32 + kg;
        int r = wv * 16 + fr;
        bf16x8 a0 = *(const bf16x8*)&As[(r * 128 + kk) ^ ((r & 7) << 3)];
        #pragma unroll
        for (int cf = 0; cf < 8; cf++) {
            int c = cf * 16 + fr;
            bf16x8 b = *(const bf16x8*)&Ws[(c * 128 + kk) ^ ((c & 7) << 3)];
            acc[cf] = __builtin_amdgcn_mfma_f32_16x16x32_bf16(a0, b, acc[cf], 0, 0, 0);
        }
    }

    const int g4 = (l >> 4) * 4;
    #pragma unroll
    for (int cf = 0; cf < 8; cf++)
        #pragma unroll
        for (int r = 0; r < 4; r++) {
            int grow = row0 + wv * 16 + g4 + r;
            if (grow < N_NODES)
                hb[(size_t)grow * 128 + cf * 16 + fr] = f2bf(acc[cf][r]);
        }
}

// ---------------- k_build (unchanged R9) ----------------
__global__ __launch_bounds__(1024) void k_build(const long long* __restrict__ buckets,
                                                const int* __restrict__ gcur,
                                                int* __restrict__ rowptr,
                                                float* __restrict__ dinv,
                                                int* __restrict__ srcs) {
    __shared__ int hist[SHR];
    __shared__ int pref[SH];
    __shared__ int wsum[16];
    const int s  = blockIdx.x;
    const int lo = s * SHR;
    const int nb = min(SHR, N_NODES - lo);
    const int n  = min(gcur[s], BCAP);
    const int t = threadIdx.x, lane = t & 63, wid = t >> 6;
    const long long* bp = buckets + (size_t)s * BCAP;

    if (t < SH) pref[t] = gcur[t];
    for (int i = t; i < SHR; i += 1024) hist[i] = 0;
    __syncthreads();
    if (wid == 0) {
        int v0 = pref[lane * 4], v1 = pref[lane * 4 + 1];
        int v2 = pref[lane * 4 + 2], v3 = pref[lane * 4 + 3];
        int sl = v0 + v1 + v2 + v3;
        int x = sl;
        #pragma unroll
        for (int d = 1; d < 64; d <<= 1) {
            int y = __shfl_up(x, d, 64);
            if (lane >= d) x += y;
        }
        int excl = x - sl;
        pref[lane * 4]     = excl;
        pref[lane * 4 + 1] = excl + v0;
        pref[lane * 4 + 2] = excl + v0 + v1;
        pref[lane * 4 + 3] = excl + v0 + v1 + v2;
        if (s == 0 && lane == 63) rowptr[N_NODES] = x;
    }
    __syncthreads();
    const int gbase = pref[s];

    for (int i = t; i < n; i += 1024) {
        atomicAdd(&hist[(int)bp[i] - lo], 1);
    }
    __syncthreads();

    {
        int idx = t;
        int v = (idx < SHR) ? hist[idx] : 0;
        int x = v;
        #pragma unroll
        for (int d = 1; d < 64; d <<= 1) {
            int y = __shfl_up(x, d, 64);
            if (lane >= d) x += y;
        }
        if (lane == 63) wsum[wid] = x;
        __syncthreads();
        if (wid == 0) {
            int sv = (lane < 16) ? wsum[lane] : 0;
            #pragma unroll
            for (int d = 1; d < 16; d <<= 1) {
                int y = __shfl_up(sv, d, 64);
                if (lane >= d) sv += y;
            }
            if (lane < 16) wsum[lane] = sv;
        }
        __syncthreads();
        int woff = (wid == 0) ? 0 : wsum[wid - 1];
        int excl = woff + (x - v);
        if (idx < nb) {
            rowptr[lo + idx] = gbase + excl;
            dinv[lo + idx]   = rsqrtf((float)(v + 1));
        }
        if (idx < SHR) hist[idx] = excl;
        __syncthreads();
    }

    for (int i = t; i < n; i += 1024) {
        long long v = bp[i];
        int d  = (int)v;
        int sv = (int)(v >> 32);
        int pos = atomicAdd(&hist[d - lo], 1);
        srcs[gbase + pos] = sv;
    }
}

// ---------------- fused kernel 2: agg128 + gemm2 ----------------
// Each block: 4 waves x 32 nodes aggregated (bf16 gather, fp32 acc, bias+relu),
// packed bf16 straight into swizzled LDS A-tile; one barrier; OC=64 MFMA; h2b out.
// agg1b intermediate eliminated (-51MB traffic).
__global__ __launch_bounds__(256) void k_aggemm(const unsigned int* __restrict__ hb,
                                                const int* __restrict__ rowptr,
                                                const int* __restrict__ srcs,
                                                const float* __restrict__ dinv,
                                                const float* __restrict__ bias,
                                                const float* __restrict__ W,
                                                unsigned short* __restrict__ h2b) {
    __shared__ __align__(16) unsigned char smem[48 * 1024];
    unsigned short* As = (unsigned short*)smem;               // 32KB: 128 rows x 128ch
    unsigned short* Ws = (unsigned short*)(smem + 32 * 1024); // 16KB: 64 cols x 128k
    const int tid = threadIdx.x;
    const int l   = tid & 63;
    const int wv  = tid >> 6;
    const int row0 = blockIdx.x * 128;
    const float2 bv = ((const float2*)bias)[l];

    for (int idx = tid; idx < 128 * 64; idx += 256) {
        int k = idx >> 6, c = idx & 63;
        Ws[(c * 128 + k) ^ ((c & 7) << 3)] = f2bf(W[idx]);
    }

    // agg phase: wave wv handles nodes row0 + wv*32 + [0,32)
    for (int t = 0; t < 32; t++) {
        const int i = row0 + wv * 32 + t;
        float2 acc = {0.f, 0.f};
        if (i < N_NODES) {
            const float di = dinv[i];
            unsigned int svv = hb[(size_t)i * 64 + l];
            const float sw = di * di;
            acc.x = bfbits2f(svv & 0xFFFFu) * sw;
            acc.y = bfbits2f(svv >> 16) * sw;

            const int start = rowptr[i], end = rowptr[i + 1];
            for (int b = start; b < end; b += 64) {
                const int eb = min(end - b, 64);
                int s = 0; float w = 0.f;
                if (l < eb) { s = srcs[b + l]; w = dinv[s] * di; }
                int j = 0;
                for (; j + 8 <= eb; j += 8) {
                    int   si[8]; float wi[8];
                    #pragma unroll
                    for (int u = 0; u < 8; u++) { si[u] = __shfl(s, j + u); wi[u] = __shfl(w, j + u); }
                    unsigned int v[8];
                    #pragma unroll
                    for (int u = 0; u < 8; u++) v[u] = hb[(size_t)si[u] * 64 + l];
                    #pragma unroll
                    for (int u = 0; u < 8; u++) {
                        acc.x = fmaf(bfbits2f(v[u] & 0xFFFFu), wi[u], acc.x);
                        acc.y = fmaf(bfbits2f(v[u] >> 16),     wi[u], acc.y);
                    }
                }
                for (; j + 4 <= eb; j += 4) {
                    int   si[4]; float wi[4];
                    #pragma unroll
                    for (int u = 0; u < 4; u++) { si[u] = __shfl(s, j + u); wi[u] = __shfl(w, j + u); }
                    unsigned int v[4];
                    #pragma unroll
                    for (int u = 0; u < 4; u++) v[u] = hb[(size_t)si[u] * 64 + l];
                    #pragma unroll
                    for (int u = 0; u < 4; u++) {
                        acc.x = fmaf(bfbits2f(v[u] & 0xFFFFu), wi[u], acc.x);
                        acc.y = fmaf(bfbits2f(v[u] >> 16),     wi[u], acc.y);
                    }
                }
                for (; j < eb; j++) {
                    const int   sj = __shfl(s, j);
                    const float wj = __shfl(w, j);
                    unsigned int v = hb[(size_t)sj * 64 + l];
                    acc.x = fmaf(bfbits2f(v & 0xFFFFu), wj, acc.x);
                    acc.y = fmaf(bfbits2f(v >> 16),     wj, acc.y);
                }
            }
            acc.x = fmaxf(acc.x + bv.x, 0.f);   // bias + relu
            acc.y = fmaxf(acc.y + bv.y, 0.f);
        }
        const int r  = wv * 32 + t;
        const int bi = (r * 128 + 2 * l) ^ ((r & 7) << 3);   // stays uint-aligned
        *(unsigned int*)&As[bi] =
            (unsigned int)f2bf(acc.x) | ((unsigned int)f2bf(acc.y) << 16);
    }
    __syncthreads();

    // gemm2 phase: OC=64, 2 row-frags/wave (rows wv*32..+31)
    f32x4 acc2[2][4];
    #pragma unroll
    for (int a = 0; a < 2; a++)
        #pragma unroll
        for (int b = 0; b < 4; b++) acc2[a][b] = {0.f, 0.f, 0.f, 0.f};

    const int fr = l & 15;
    const int kg = (l >> 4) * 8;
    #pragma unroll
    for (int ks = 0; ks < 4; ks++) {
        const int kk = ks * 32 + kg;
        bf16x8 a0, a1;
        {
            int r = wv * 32 + fr;
            a0 = *(const bf16x8*)&As[(r * 128 + kk) ^ ((r & 7) << 3)];
            r += 16;
            a1 = *(const bf16x8*)&As[(r * 128 + kk) ^ ((r & 7) << 3)];
        }
        #pragma unroll
        for (int cf = 0; cf < 4; cf++) {
            int c = cf * 16 + fr;
            bf16x8 b = *(const bf16x8*)&Ws[(c * 128 + kk) ^ ((c & 7) << 3)];
            acc2[0][cf] = __builtin_amdgcn_mfma_f32_16x16x32_bf16(a0, b, acc2[0][cf], 0, 0, 0);
            acc2[1][cf] = __builtin_amdgcn_mfma_f32_16x16x32_bf16(a1, b, acc2[1][cf], 0, 0, 0);
        }
    }

    const int g4 = (l >> 4) * 4;
    #pragma unroll
    for (int rf = 0; rf < 2; rf++)
        #pragma unroll
        for (int cf = 0; cf < 4; cf++)
            #pragma unroll
            for (int r = 0; r < 4; r++) {
                int grow = row0 + wv * 32 + rf * 16 + g4 + r;
                if (grow < N_NODES)
                    h2b[(size_t)grow * 64 + cf * 16 + fr] = f2bf(acc2[rf][cf][r]);
            }
}

// ---------------- agg64 (unchanged R9) ----------------
__global__ __launch_bounds__(256) void k_agg64bf(const unsigned short* __restrict__ hb,
                                                 const int* __restrict__ rowptr,
                                                 const int* __restrict__ srcs,
                                                 const float* __restrict__ dinv,
                                                 const float* __restrict__ bias,
                                                 float* __restrict__ out,
                                                 int relu) {
    const int l = threadIdx.x & 63;
    const int wv0 = blockIdx.x * 4 + (threadIdx.x >> 6);
    const float bi = bias[l];

    for (int i = wv0; i < N_NODES; i += AGG_BLOCKS * 4) {
        const float di = dinv[i];
        float acc = bfbits2f((unsigned int)hb[(size_t)i * 64 + l]) * (di * di);

        const int start = rowptr[i], end = rowptr[i + 1];
        for (int b = start; b < end; b += 64) {
            const int eb = min(end - b, 64);
            int s = 0; float w = 0.f;
            if (l < eb) { s = srcs[b + l]; w = dinv[s] * di; }
            int j = 0;
            for (; j + 8 <= eb; j += 8) {
                int   si[8]; float wi[8];
                #pragma unroll
                for (int u = 0; u < 8; u++) { si[u] = __shfl(s, j + u); wi[u] = __shfl(w, j + u); }
                unsigned short v[8];
                #pragma unroll
                for (int u = 0; u < 8; u++) v[u] = hb[(size_t)si[u] * 64 + l];
                #pragma unroll
                for (int u = 0; u < 8; u++) acc = fmaf(bfbits2f((unsigned int)v[u]), wi[u], acc);
            }
            for (; j + 4 <= eb; j += 4) {
                int   si[4]; float wi[4];
                #pragma unroll
                for (int u = 0; u < 4; u++) { si[u] = __shfl(s, j + u); wi[u] = __shfl(w, j + u); }
                unsigned short v[4];
                #pragma unroll
                for (int u = 0; u < 4; u++) v[u] = hb[(size_t)si[u] * 64 + l];
                #pragma unroll
                for (int u = 0; u < 4; u++) acc = fmaf(bfbits2f((unsigned int)v[u]), wi[u], acc);
            }
            for (; j < eb; j++) {
                const int   sj = __shfl(s, j);
                const float wj = __shfl(w, j);
                acc = fmaf(bfbits2f((unsigned int)hb[(size_t)sj * 64 + l]), wj, acc);
            }
        }
        acc += bi;
        if (relu) acc = fmaxf(acc, 0.f);
        out[(size_t)i * 64 + l] = acc;
    }
}

// ---------------- launch ----------------

extern "C" void kernel_launch(void* const* d_in, const int* in_sizes, int n_in,
                              void* d_out, int out_size, void* d_ws, size_t ws_size,
                              hipStream_t stream) {
    const float* x  = (const float*)d_in[0];
    const int*   ei = (const int*)d_in[1];
    const float* W1 = (const float*)d_in[2];
    const float* b1 = (const float*)d_in[3];
    const float* W2 = (const float*)d_in[4];
    const float* b2 = (const float*)d_in[5];
    float* out = (float*)d_out;

    char* p = (char*)d_ws;
    size_t used = 0;
    auto alloc = [&](size_t bytes) {
        void* q = (void*)p;
        size_t pad = (bytes + 255) & ~(size_t)255;
        p += pad;
        used += pad;
        return q;
    };
    int*   rowptr = (int*)alloc(sizeof(int) * (N_NODES + 1));
    float* dinv   = (float*)alloc(sizeof(float) * N_NODES);
    int*   gcur   = (int*)alloc(sizeof(int) * SH);
    int*   srcs   = (int*)alloc(sizeof(int) * N_EDGES);
    long long* buckets = (long long*)alloc(sizeof(long long) * (size_t)SH * BCAP); // 14.75MB
    unsigned short* h1b = (unsigned short*)alloc(sizeof(unsigned short) * (size_t)N_NODES * 128); // 25.6MB (no alias: written concurrently with buckets)
    unsigned short* h2b = (unsigned short*)alloc(sizeof(unsigned short) * (size_t)N_NODES * 64);  // 12.8MB

    if (used > ws_size) return;

    hipMemsetAsync(gcur, 0, sizeof(int) * SH, stream);
    k_fused1<<<BK_NBLK + GM_NBLK, 512, 0, stream>>>(ei, gcur, buckets, x, W1, h1b);
    k_build<<<SH, 1024, 0, stream>>>(buckets, gcur, rowptr, dinv, srcs);
    k_aggemm<<<GM_NBLK, 256, 0, stream>>>((const unsigned int*)h1b, rowptr, srcs, dinv, b1, W2, h2b);
    k_agg64bf<<<AGG_BLOCKS, 256, 0, stream>>>(h2b, rowptr, srcs, dinv, b2, out, 0);
}

// Round 11
// 184.171 us; speedup vs baseline: 1.5035x; 1.5035x over previous
//
#include <hip/hip_runtime.h>
#include <cstdint>
#include <cstddef>

#define N_NODES 100000
#define N_EDGES 1600000
#define IN_CH   128
#define HID_CH  128
#define OUT_CH  64

#define AGG_BLOCKS 2048

#define SH    256
#define SHR   391        // ceil(100000/256)
#define BCAP  7200       // mean 6250, ~12 sigma slack
#define BK_CHUNK 4096
#define BK_NBLK ((N_EDGES + BK_CHUNK - 1) / BK_CHUNK)   // 391
#define GM_NBLK ((N_NODES + 127) / 128)                  // 782

__device__ __forceinline__ unsigned short f2bf(float f) {
    unsigned int u = __float_as_uint(f);
    unsigned int r = (u + 0x7FFFu + ((u >> 16) & 1u)) >> 16;   // RNE
    return (unsigned short)r;
}
__device__ __forceinline__ float bfbits2f(unsigned int lo16) {
    return __uint_as_float(lo16 << 16);
}

typedef __attribute__((ext_vector_type(8))) short bf16x8;
typedef __attribute__((ext_vector_type(4))) float f32x4;

// ---------------- fused kernel 1: bucket (blocks 0..390) ∥ gemm1 (391..1172) ----------------
// Bucket: scatter/memory-bound. Gemm1: MFMA-bound. Independent work, one dispatch.
// NOTE (R10 lesson): occupancy-hungry gather must NOT be fused with LDS-heavy
// MFMA (k_aggemm: 48KB LDS -> 18% occupancy -> 173us). This fusion is safe:
// both paths are transient, block-scoped, and neither needs high residency.
__global__ __launch_bounds__(512) void k_fused1(const int* __restrict__ ei,
                                                int* __restrict__ gcur,
                                                long long* __restrict__ buckets,
                                                const float* __restrict__ A,
                                                const float* __restrict__ W,
                                                unsigned short* __restrict__ hb) {
    __shared__ __align__(16) unsigned char smem[64 * 1024];
    const int tid = threadIdx.x;

    if (blockIdx.x < BK_NBLK) {
        // ---- bucket path ----
        int (*scount)[SH] = (int(*)[SH])smem;                 // 8KB
        int (*sbase)[SH]  = (int(*)[SH])(smem + 8 * SH * 4);  // 8KB
        const int w    = tid >> 6;
        const int base = blockIdx.x * BK_CHUNK;
        for (int i = tid; i < 8 * SH; i += 512) ((int*)scount)[i] = 0;
        __syncthreads();
        int dv[8], sv[8], shd[8], rk[8];
        #pragma unroll
        for (int k = 0; k < 8; k++) {
            int e = base + k * 512 + tid;
            if (e < N_EDGES) {
                dv[k] = __builtin_nontemporal_load(ei + N_EDGES + e);
                sv[k] = __builtin_nontemporal_load(ei + e);
                shd[k] = dv[k] / SHR;
                rk[k] = atomicAdd(&scount[w][shd[k]], 1);
            } else shd[k] = -1;
        }
        __syncthreads();
        if (tid < SH) {
            int c[8], tot = 0;
            #pragma unroll
            for (int q = 0; q < 8; q++) { c[q] = scount[q][tid]; tot += c[q]; }
            int run = atomicAdd(&gcur[tid], tot);
            #pragma unroll
            for (int q = 0; q < 8; q++) { sbase[q][tid] = run; run += c[q]; }
        }
        __syncthreads();
        #pragma unroll
        for (int k = 0; k < 8; k++) {
            if (shd[k] >= 0) {
                int pos = sbase[w][shd[k]] + rk[k];
                if (pos < BCAP)
                    buckets[(size_t)shd[k] * BCAP + pos] =
                        ((long long)sv[k] << 32) | (unsigned int)dv[k];
            }
        }
        return;
    }

    // ---- gemm1 path: 8 waves x 16 rows, OC=128 ----
    unsigned short* As = (unsigned short*)smem;              // 32KB
    unsigned short* Ws = (unsigned short*)(smem + 32 * 1024);// 32KB
    const int l   = tid & 63;
    const int wv  = tid >> 6;                                // 0..7
    const int row0 = (blockIdx.x - BK_NBLK) * 128;

    #pragma unroll
    for (int it = 0; it < 8; it++) {
        int idx4 = it * 512 + tid;                           // 4096 float4
        int r = idx4 >> 5, c4 = idx4 & 31;
        int gr = row0 + r; if (gr >= N_NODES) gr = N_NODES - 1;
        float4 v = ((const float4*)(A + (size_t)gr * 128))[c4];
        int bi = (r * 128 + c4 * 4) ^ ((r & 7) << 3);
        ushort4 pk;
        pk.x = f2bf(v.x); pk.y = f2bf(v.y); pk.z = f2bf(v.z); pk.w = f2bf(v.w);
        *(ushort4*)&As[bi] = pk;
    }
    for (int idx = tid; idx < 128 * 128; idx += 512) {
        int k = idx >> 7, c = idx & 127;
        Ws[(c * 128 + k) ^ ((c & 7) << 3)] = f2bf(W[idx]);
    }
    __syncthreads();

    f32x4 acc[8];
    #pragma unroll
    for (int cf = 0; cf < 8; cf++) acc[cf] = {0.f, 0.f, 0.f, 0.f};
    const int fr = l & 15;
    const int kg = (l >> 4) * 8;

    #pragma unroll
    for (int ks = 0; ks < 4; ks++) {
        const int kk = ks * 32 + kg;
        int r = wv * 16 + fr;
        bf16x8 a0 = *(const bf16x8*)&As[(r * 128 + kk) ^ ((r & 7) << 3)];
        #pragma unroll
        for (int cf = 0; cf < 8; cf++) {
            int c = cf * 16 + fr;
            bf16x8 b = *(const bf16x8*)&Ws[(c * 128 + kk) ^ ((c & 7) << 3)];
            acc[cf] = __builtin_amdgcn_mfma_f32_16x16x32_bf16(a0, b, acc[cf], 0, 0, 0);
        }
    }

    const int g4 = (l >> 4) * 4;
    #pragma unroll
    for (int cf = 0; cf < 8; cf++)
        #pragma unroll
        for (int r = 0; r < 4; r++) {
            int grow = row0 + wv * 16 + g4 + r;
            if (grow < N_NODES)
                hb[(size_t)grow * 128 + cf * 16 + fr] = f2bf(acc[cf][r]);
        }
}

// ---------------- k_build ----------------
__global__ __launch_bounds__(1024) void k_build(const long long* __restrict__ buckets,
                                                const int* __restrict__ gcur,
                                                int* __restrict__ rowptr,
                                                float* __restrict__ dinv,
                                                int* __restrict__ srcs) {
    __shared__ int hist[SHR];
    __shared__ int pref[SH];
    __shared__ int wsum[16];
    const int s  = blockIdx.x;
    const int lo = s * SHR;
    const int nb = min(SHR, N_NODES - lo);
    const int n  = min(gcur[s], BCAP);
    const int t = threadIdx.x, lane = t & 63, wid = t >> 6;
    const long long* bp = buckets + (size_t)s * BCAP;

    if (t < SH) pref[t] = gcur[t];
    for (int i = t; i < SHR; i += 1024) hist[i] = 0;
    __syncthreads();
    if (wid == 0) {
        int v0 = pref[lane * 4], v1 = pref[lane * 4 + 1];
        int v2 = pref[lane * 4 + 2], v3 = pref[lane * 4 + 3];
        int sl = v0 + v1 + v2 + v3;
        int x = sl;
        #pragma unroll
        for (int d = 1; d < 64; d <<= 1) {
            int y = __shfl_up(x, d, 64);
            if (lane >= d) x += y;
        }
        int excl = x - sl;
        pref[lane * 4]     = excl;
        pref[lane * 4 + 1] = excl + v0;
        pref[lane * 4 + 2] = excl + v0 + v1;
        pref[lane * 4 + 3] = excl + v0 + v1 + v2;
        if (s == 0 && lane == 63) rowptr[N_NODES] = x;
    }
    __syncthreads();
    const int gbase = pref[s];

    for (int i = t; i < n; i += 1024) {
        atomicAdd(&hist[(int)bp[i] - lo], 1);
    }
    __syncthreads();

    {
        int idx = t;
        int v = (idx < SHR) ? hist[idx] : 0;
        int x = v;
        #pragma unroll
        for (int d = 1; d < 64; d <<= 1) {
            int y = __shfl_up(x, d, 64);
            if (lane >= d) x += y;
        }
        if (lane == 63) wsum[wid] = x;
        __syncthreads();
        if (wid == 0) {
            int sv = (lane < 16) ? wsum[lane] : 0;
            #pragma unroll
            for (int d = 1; d < 16; d <<= 1) {
                int y = __shfl_up(sv, d, 64);
                if (lane >= d) sv += y;
            }
            if (lane < 16) wsum[lane] = sv;
        }
        __syncthreads();
        int woff = (wid == 0) ? 0 : wsum[wid - 1];
        int excl = woff + (x - v);
        if (idx < nb) {
            rowptr[lo + idx] = gbase + excl;
            dinv[lo + idx]   = rsqrtf((float)(v + 1));
        }
        if (idx < SHR) hist[idx] = excl;
        __syncthreads();
    }

    for (int i = t; i < n; i += 1024) {
        long long v = bp[i];
        int d  = (int)v;
        int sv = (int)(v >> 32);
        int pos = atomicAdd(&hist[d - lo], 1);
        srcs[gbase + pos] = sv;
    }
}

// ---------------- agg128 (R9 version: high-occupancy grid-stride) ----------------
__global__ __launch_bounds__(256) void k_agg128bf(const unsigned int* __restrict__ hb,
                                                  const int* __restrict__ rowptr,
                                                  const int* __restrict__ srcs,
                                                  const float* __restrict__ dinv,
                                                  const float* __restrict__ bias,
                                                  unsigned int* __restrict__ outb,
                                                  int relu) {
    const int l = threadIdx.x & 63;
    const int wv0 = blockIdx.x * 4 + (threadIdx.x >> 6);
    const float2 bv = ((const float2*)bias)[l];

    for (int i = wv0; i < N_NODES; i += AGG_BLOCKS * 4) {
        const float di = dinv[i];
        unsigned int svv = hb[(size_t)i * 64 + l];
        const float sw = di * di;
        float2 acc;
        acc.x = bfbits2f(svv & 0xFFFFu) * sw;
        acc.y = bfbits2f(svv >> 16) * sw;

        const int start = rowptr[i], end = rowptr[i + 1];
        for (int b = start; b < end; b += 64) {
            const int eb = min(end - b, 64);
            int s = 0; float w = 0.f;
            if (l < eb) { s = srcs[b + l]; w = dinv[s] * di; }
            int j = 0;
            for (; j + 8 <= eb; j += 8) {
                int   si[8]; float wi[8];
                #pragma unroll
                for (int u = 0; u < 8; u++) { si[u] = __shfl(s, j + u); wi[u] = __shfl(w, j + u); }
                unsigned int v[8];
                #pragma unroll
                for (int u = 0; u < 8; u++) v[u] = hb[(size_t)si[u] * 64 + l];
                #pragma unroll
                for (int u = 0; u < 8; u++) {
                    acc.x = fmaf(bfbits2f(v[u] & 0xFFFFu), wi[u], acc.x);
                    acc.y = fmaf(bfbits2f(v[u] >> 16),     wi[u], acc.y);
                }
            }
            for (; j + 4 <= eb; j += 4) {
                int   si[4]; float wi[4];
                #pragma unroll
                for (int u = 0; u < 4; u++) { si[u] = __shfl(s, j + u); wi[u] = __shfl(w, j + u); }
                unsigned int v[4];
                #pragma unroll
                for (int u = 0; u < 4; u++) v[u] = hb[(size_t)si[u] * 64 + l];
                #pragma unroll
                for (int u = 0; u < 4; u++) {
                    acc.x = fmaf(bfbits2f(v[u] & 0xFFFFu), wi[u], acc.x);
                    acc.y = fmaf(bfbits2f(v[u] >> 16),     wi[u], acc.y);
                }
            }
            for (; j < eb; j++) {
                const int   sj = __shfl(s, j);
                const float wj = __shfl(w, j);
                unsigned int v = hb[(size_t)sj * 64 + l];
                acc.x = fmaf(bfbits2f(v & 0xFFFFu), wj, acc.x);
                acc.y = fmaf(bfbits2f(v >> 16),     wj, acc.y);
            }
        }
        acc.x += bv.x; acc.y += bv.y;
        if (relu) { acc.x = fmaxf(acc.x, 0.f); acc.y = fmaxf(acc.y, 0.f); }
        outb[(size_t)i * 64 + l] =
            (unsigned int)f2bf(acc.x) | ((unsigned int)f2bf(acc.y) << 16);
    }
}

// ---------------- gemm2: bf16-input MFMA, OC=64 ----------------
__global__ __launch_bounds__(256) void k_gemm2(const unsigned short* __restrict__ A,
                                               const float* __restrict__ W,
                                               unsigned short* __restrict__ hb) {
    __shared__ unsigned short As[128 * 128];
    __shared__ unsigned short Ws[64 * 128];
    const int tid = threadIdx.x;
    const int l   = tid & 63;
    const int wv  = tid >> 6;
    const int row0 = blockIdx.x * 128;

    #pragma unroll
    for (int it = 0; it < 8; it++) {
        int idx8 = it * 256 + tid;
        int r = idx8 >> 4, c8 = idx8 & 15;
        int gr = row0 + r; if (gr >= N_NODES) gr = N_NODES - 1;
        uint4 v = ((const uint4*)(A + (size_t)gr * 128))[c8];
        int bi = (r * 128 + c8 * 8) ^ ((r & 7) << 3);
        *(uint4*)&As[bi] = v;
    }
    for (int idx = tid; idx < 128 * 64; idx += 256) {
        int k = idx >> 6, c = idx & 63;
        Ws[(c * 128 + k) ^ ((c & 7) << 3)] = f2bf(W[idx]);
    }
    __syncthreads();

    f32x4 acc[2][4];
    #pragma unroll
    for (int a = 0; a < 2; a++)
        #pragma unroll
        for (int b = 0; b < 4; b++) acc[a][b] = {0.f, 0.f, 0.f, 0.f};

    const int fr = l & 15;
    const int kg = (l >> 4) * 8;

    #pragma unroll
    for (int ks = 0; ks < 4; ks++) {
        const int kk = ks * 32 + kg;
        bf16x8 a0, a1;
        {
            int r = wv * 32 + fr;
            a0 = *(const bf16x8*)&As[(r * 128 + kk) ^ ((r & 7) << 3)];
            r += 16;
            a1 = *(const bf16x8*)&As[(r * 128 + kk) ^ ((r & 7) << 3)];
        }
        #pragma unroll
        for (int cf = 0; cf < 4; cf++) {
            int c = cf * 16 + fr;
            bf16x8 b = *(const bf16x8*)&Ws[(c * 128 + kk) ^ ((c & 7) << 3)];
            acc[0][cf] = __builtin_amdgcn_mfma_f32_16x16x32_bf16(a0, b, acc[0][cf], 0, 0, 0);
            acc[1][cf] = __builtin_amdgcn_mfma_f32_16x16x32_bf16(a1, b, acc[1][cf], 0, 0, 0);
        }
    }

    const int g4 = (l >> 4) * 4;
    #pragma unroll
    for (int rf = 0; rf < 2; rf++)
        #pragma unroll
        for (int cf = 0; cf < 4; cf++)
            #pragma unroll
            for (int r = 0; r < 4; r++) {
                int grow = row0 + wv * 32 + rf * 16 + g4 + r;
                if (grow < N_NODES)
                    hb[(size_t)grow * 64 + cf * 16 + fr] = f2bf(acc[rf][cf][r]);
            }
}

// ---------------- agg64 ----------------
__global__ __launch_bounds__(256) void k_agg64bf(const unsigned short* __restrict__ hb,
                                                 const int* __restrict__ rowptr,
                                                 const int* __restrict__ srcs,
                                                 const float* __restrict__ dinv,
                                                 const float* __restrict__ bias,
                                                 float* __restrict__ out,
                                                 int relu) {
    const int l = threadIdx.x & 63;
    const int wv0 = blockIdx.x * 4 + (threadIdx.x >> 6);
    const float bi = bias[l];

    for (int i = wv0; i < N_NODES; i += AGG_BLOCKS * 4) {
        const float di = dinv[i];
        float acc = bfbits2f((unsigned int)hb[(size_t)i * 64 + l]) * (di * di);

        const int start = rowptr[i], end = rowptr[i + 1];
        for (int b = start; b < end; b += 64) {
            const int eb = min(end - b, 64);
            int s = 0; float w = 0.f;
            if (l < eb) { s = srcs[b + l]; w = dinv[s] * di; }
            int j = 0;
            for (; j + 8 <= eb; j += 8) {
                int   si[8]; float wi[8];
                #pragma unroll
                for (int u = 0; u < 8; u++) { si[u] = __shfl(s, j + u); wi[u] = __shfl(w, j + u); }
                unsigned short v[8];
                #pragma unroll
                for (int u = 0; u < 8; u++) v[u] = hb[(size_t)si[u] * 64 + l];
                #pragma unroll
                for (int u = 0; u < 8; u++) acc = fmaf(bfbits2f((unsigned int)v[u]), wi[u], acc);
            }
            for (; j + 4 <= eb; j += 4) {
                int   si[4]; float wi[4];
                #pragma unroll
                for (int u = 0; u < 4; u++) { si[u] = __shfl(s, j + u); wi[u] = __shfl(w, j + u); }
                unsigned short v[4];
                #pragma unroll
                for (int u = 0; u < 4; u++) v[u] = hb[(size_t)si[u] * 64 + l];
                #pragma unroll
                for (int u = 0; u < 4; u++) acc = fmaf(bfbits2f((unsigned int)v[u]), wi[u], acc);
            }
            for (; j < eb; j++) {
                const int   sj = __shfl(s, j);
                const float wj = __shfl(w, j);
                acc = fmaf(bfbits2f((unsigned int)hb[(size_t)sj * 64 + l]), wj, acc);
            }
        }
        acc += bi;
        if (relu) acc = fmaxf(acc, 0.f);
        out[(size_t)i * 64 + l] = acc;
    }
}

// ---------------- launch ----------------

extern "C" void kernel_launch(void* const* d_in, const int* in_sizes, int n_in,
                              void* d_out, int out_size, void* d_ws, size_t ws_size,
                              hipStream_t stream) {
    const float* x  = (const float*)d_in[0];
    const int*   ei = (const int*)d_in[1];
    const float* W1 = (const float*)d_in[2];
    const float* b1 = (const float*)d_in[3];
    const float* W2 = (const float*)d_in[4];
    const float* b2 = (const float*)d_in[5];
    float* out = (float*)d_out;

    char* p = (char*)d_ws;
    size_t used = 0;
    auto alloc = [&](size_t bytes) {
        void* q = (void*)p;
        size_t pad = (bytes + 255) & ~(size_t)255;
        p += pad;
        used += pad;
        return q;
    };
    int*   rowptr = (int*)alloc(sizeof(int) * (N_NODES + 1));
    float* dinv   = (float*)alloc(sizeof(float) * N_NODES);
    int*   gcur   = (int*)alloc(sizeof(int) * SH);
    int*   srcs   = (int*)alloc(sizeof(int) * N_EDGES);
    // region B: buckets (14.75MB) then agg1b (25.6MB) — buckets dead after k_build,
    // agg1b written only after k_build completes (stream-ordered).
    void*  regB   = alloc(sizeof(unsigned int) * (size_t)N_NODES * 64);   // 25.6MB
    long long* buckets = (long long*)regB;
    unsigned int* agg1b = (unsigned int*)regB;
    // h1b NOT aliased: written by fused1 concurrently with buckets.
    unsigned short* h1b = (unsigned short*)alloc(sizeof(unsigned short) * (size_t)N_NODES * 128); // 25.6MB
    unsigned short* h2b = (unsigned short*)alloc(sizeof(unsigned short) * (size_t)N_NODES * 64);  // 12.8MB

    if (used > ws_size) return;

    hipMemsetAsync(gcur, 0, sizeof(int) * SH, stream);
    k_fused1<<<BK_NBLK + GM_NBLK, 512, 0, stream>>>(ei, gcur, buckets, x, W1, h1b);
    k_build<<<SH, 1024, 0, stream>>>(buckets, gcur, rowptr, dinv, srcs);
    k_agg128bf<<<AGG_BLOCKS, 256, 0, stream>>>((const unsigned int*)h1b, rowptr, srcs, dinv, b1, agg1b, 1);
    k_gemm2<<<GM_NBLK, 256, 0, stream>>>((const unsigned short*)agg1b, W2, h2b);
    k_agg64bf<<<AGG_BLOCKS, 256, 0, stream>>>(h2b, rowptr, srcs, dinv, b2, out, 0);
}